// Round 1
// baseline (697.523 us; speedup 1.0000x reference)
//
#include <hip/hip_runtime.h>
#include <hip/hip_bf16.h>
#include <cstdint>
#include <cstddef>

// HierarchicalAttention on MI355X (gfx950).
// Pipeline: cast(x,wqkv,wproj)->bf16 | qkv GEMM (bf16 MFMA) | window attention
// (MFMA QK^T + fp32 softmax + MFMA PV) | proj GEMM (bf16 MFMA, fp32 out).
//
// Workspace layout (total 343,932,928 B):
//   [0)            x_bf16     [32768,1024]  67,108,864 B
//   [67108864)     wqkv_bf16  [3072,1024]    6,291,456 B
//   [73400320)     wproj_bf16 [1024,1024]    2,097,152 B
//   [75497472)     qkv_bf16   [32768,3072] 201,326,592 B
//   [276824064)    attn_bf16  [32768,1024]  67,108,864 B

typedef __attribute__((ext_vector_type(8))) short short8;
typedef __attribute__((ext_vector_type(4))) float float4v;

static __device__ __forceinline__ void async16(void* lds, const void* g) {
  // global -> LDS direct copy, 16B per lane; LDS dest = wave-uniform base + lane*16
  __builtin_amdgcn_global_load_lds((const __attribute__((address_space(1))) void*)g,
                                   (__attribute__((address_space(3))) void*)lds,
                                   16, 0, 0);
}

static __device__ __forceinline__ unsigned short f2bf_bits(float x) {
  unsigned int u = __float_as_uint(x);
  unsigned int r = (u + 0x7fffu + ((u >> 16) & 1u)) >> 16;  // RNE
  return (unsigned short)r;
}

// ---------------- cast fp32 -> bf16 (vectorized, n divisible by 1024) -------
__global__ __launch_bounds__(256) void cast_f32_to_bf16(
    const float* __restrict__ in, unsigned short* __restrict__ out, int n4) {
  int i = blockIdx.x * 256 + threadIdx.x;
  if (i >= n4) return;
  float4 v = ((const float4*)in)[i];
  ushort4 o;
  o.x = f2bf_bits(v.x); o.y = f2bf_bits(v.y);
  o.z = f2bf_bits(v.z); o.w = f2bf_bits(v.w);
  ((ushort4*)out)[i] = o;
}

// ---------------- GEMM: C[M,N] = A[M,K] * B[N,K]^T + bias ------------------
// m97 structure: 128x128 tile, BK=32, 4 waves in 2x2, each wave 64x64 (4x4
// tiles of mfma_f32_16x16x32_bf16), global_load_lds width=16 staging,
// 2-barrier K-loop. M,N,K divisible by 128/128/32; no bounds checks.
template<bool OUT_BF16>
__global__ __launch_bounds__(256) void gemm_bt(
    const unsigned short* __restrict__ A,   // [M,K] bf16 bits
    const unsigned short* __restrict__ B,   // [N,K] bf16 bits
    const float* __restrict__ bias,         // [N]
    void* __restrict__ Cout,                // [M,N] bf16 or fp32
    int M, int N, int K, int mtiles)
{
  __shared__ unsigned short As[128 * 32];   // 8 KB
  __shared__ unsigned short Bs[128 * 32];   // 8 KB

  const int t    = threadIdx.x;
  const int wave = t >> 6;
  const int lane = t & 63;
  const int bm   = blockIdx.x % mtiles;
  const int bn   = blockIdx.x / mtiles;
  const int wm   = (wave >> 1) * 64;
  const int wn   = (wave & 1) * 64;
  const int lr   = lane & 15;        // row within 16-tile for A/B frags
  const int lk   = (lane >> 4) * 8;  // k offset within BK=32

  // staging: thread t covers LDS elems [t*8, t*8+8) and [2048+t*8, ...)
  const int srow = t >> 2;           // 0..63
  const int scol = (t & 3) << 3;     // 0,8,16,24
  const unsigned short* Ag = A + (size_t)(bm * 128 + srow) * K + scol;
  const unsigned short* Bg = B + (size_t)(bn * 128 + srow) * K + scol;
  unsigned short* Asw = As + wave * 512;  // wave-uniform LDS base
  unsigned short* Bsw = Bs + wave * 512;

  float4v acc[4][4];
  #pragma unroll
  for (int i = 0; i < 4; ++i)
    #pragma unroll
    for (int j = 0; j < 4; ++j) acc[i][j] = (float4v){0.f, 0.f, 0.f, 0.f};

  for (int k0 = 0; k0 < K; k0 += 32) {
    async16(Asw,        Ag + k0);
    async16(Asw + 2048, Ag + (size_t)64 * K + k0);
    async16(Bsw,        Bg + k0);
    async16(Bsw + 2048, Bg + (size_t)64 * K + k0);
    __syncthreads();  // drains vmcnt (global_load_lds) + barrier

    short8 af[4], bfr[4];
    #pragma unroll
    for (int i = 0; i < 4; ++i)
      af[i] = *(const short8*)(As + (wm + i * 16 + lr) * 32 + lk);
    #pragma unroll
    for (int j = 0; j < 4; ++j)
      bfr[j] = *(const short8*)(Bs + (wn + j * 16 + lr) * 32 + lk);
    #pragma unroll
    for (int i = 0; i < 4; ++i)
      #pragma unroll
      for (int j = 0; j < 4; ++j)
        acc[i][j] = __builtin_amdgcn_mfma_f32_16x16x32_bf16(af[i], bfr[j], acc[i][j], 0, 0, 0);
    __syncthreads();  // protect LDS before next staging
  }

  // epilogue: C/D layout col=lane&15, row=(lane>>4)*4+reg (m89-verified)
  const int rbase = bm * 128 + wm + (lane >> 4) * 4;
  const int cbase = bn * 128 + wn + lr;
  #pragma unroll
  for (int j = 0; j < 4; ++j) {
    const int col = cbase + j * 16;
    const float bv = bias[col];
    #pragma unroll
    for (int i = 0; i < 4; ++i) {
      const int row = rbase + i * 16;
      #pragma unroll
      for (int r = 0; r < 4; ++r) {
        float v = acc[i][j][r] + bv;
        if (OUT_BF16)
          ((unsigned short*)Cout)[(size_t)(row + r) * N + col] = f2bf_bits(v);
        else
          ((float*)Cout)[(size_t)(row + r) * N + col] = v;
      }
    }
  }
}

// ---------------- window attention --------------------------------------
// One block (4 waves) per 64-token window. Wave w owns query strip
// [w*16, w*16+16). S=QK^T and O=PV via mfma_f32_16x16x32_bf16; softmax fp32.
__global__ __launch_bounds__(256) void win_attn(
    const unsigned short* __restrict__ qkv,  // [32768, 3072] bf16
    unsigned short* __restrict__ out)        // [32768, 1024] bf16
{
  __shared__ unsigned short Qs[64 * 64];  // 8 KB each
  __shared__ unsigned short Ks[64 * 64];
  __shared__ unsigned short Vt[64 * 64];  // V transposed: Vt[d][key]
  __shared__ unsigned short Ps[64 * 64];

  const int t    = threadIdx.x;
  const int wave = t >> 6;
  const int lane = t & 63;
  const int wid  = blockIdx.x;          // 0..8191
  const int h    = (wid >> 7) & 15;
  const int b    = wid >> 11;
  const int wi   = wid & 127;
  const int tok0 = b * 8192 + wi * 64;

  const unsigned short* qb = qkv + (size_t)tok0 * 3072 + h * 64;
  const unsigned short* kb = qb + 1024;
  const unsigned short* vb = qb + 2048;

  {
    // Q,K: async 16B/lane; LDS elem offset = t*8 + o*2048 (row-major [64][64])
    const int row = t >> 3;          // 0..31
    const int col = (t & 7) << 3;    // 0..56
    unsigned short* Qw = Qs + wave * 512;
    unsigned short* Kw = Ks + wave * 512;
    #pragma unroll
    for (int o = 0; o < 2; ++o) {
      async16(Qw + o * 2048, qb + (size_t)(o * 32 + row) * 3072 + col);
      async16(Kw + o * 2048, kb + (size_t)(o * 32 + row) * 3072 + col);
    }
    // V transposed: lane reads V[key][d0..d0+7], writes Vt[d][key]
    // (LDS write bank = (lane/2)%32 -> 2-way, free per m136)
    const int key = lane;
    const int d0  = wave * 8;
    #pragma unroll
    for (int o = 0; o < 2; ++o) {
      const int d = d0 + o * 32;
      ushort4 r0 = *(const ushort4*)(vb + (size_t)key * 3072 + d);
      ushort4 r1 = *(const ushort4*)(vb + (size_t)key * 3072 + d + 4);
      Vt[(d + 0) * 64 + key] = r0.x; Vt[(d + 1) * 64 + key] = r0.y;
      Vt[(d + 2) * 64 + key] = r0.z; Vt[(d + 3) * 64 + key] = r0.w;
      Vt[(d + 4) * 64 + key] = r1.x; Vt[(d + 5) * 64 + key] = r1.y;
      Vt[(d + 6) * 64 + key] = r1.z; Vt[(d + 7) * 64 + key] = r1.w;
    }
  }
  __syncthreads();

  const int lr = lane & 15;
  const int lq = lane >> 4;

  // S = Q K^T : A-frag rows = wave strip, contiguous ds_read_b128
  short8 qa[2];
  #pragma unroll
  for (int k2 = 0; k2 < 2; ++k2)
    qa[k2] = *(const short8*)(Qs + (wave * 16 + lr) * 64 + k2 * 32 + lq * 8);

  float4v s[4];
  #pragma unroll
  for (int jt = 0; jt < 4; ++jt) {
    float4v a = (float4v){0.f, 0.f, 0.f, 0.f};
    #pragma unroll
    for (int k2 = 0; k2 < 2; ++k2) {
      short8 kf = *(const short8*)(Ks + (jt * 16 + lr) * 64 + k2 * 32 + lq * 8);
      a = __builtin_amdgcn_mfma_f32_16x16x32_bf16(qa[k2], kf, a, 0, 0, 0);
    }
    s[jt] = a;
  }

  // softmax over keys; row = wave*16 + lq*4 + r, cols spread over jt (reg) and
  // lane&15 (16-lane groups share lq -> xor-shuffle 1,2,4,8)
  const float scale = 0.125f;  // 1/sqrt(64)
  float pr[4][4];
  #pragma unroll
  for (int r = 0; r < 4; ++r) {
    float m = s[0][r];
    #pragma unroll
    for (int jt = 1; jt < 4; ++jt) m = fmaxf(m, s[jt][r]);
    #pragma unroll
    for (int off = 1; off < 16; off <<= 1) m = fmaxf(m, __shfl_xor(m, off));
    float sum = 0.f;
    #pragma unroll
    for (int jt = 0; jt < 4; ++jt) {
      float e = __expf((s[jt][r] - m) * scale);
      pr[jt][r] = e; sum += e;
    }
    #pragma unroll
    for (int off = 1; off < 16; off <<= 1) sum += __shfl_xor(sum, off);
    float inv = 1.0f / sum;
    #pragma unroll
    for (int jt = 0; jt < 4; ++jt) pr[jt][r] *= inv;
  }

  // P: C-layout -> LDS -> A-layout (m120-verified round trip)
  #pragma unroll
  for (int jt = 0; jt < 4; ++jt)
    #pragma unroll
    for (int r = 0; r < 4; ++r)
      Ps[(wave * 16 + lq * 4 + r) * 64 + jt * 16 + lr] = f2bf_bits(pr[jt][r]);
  __syncthreads();

  short8 pa[2];
  #pragma unroll
  for (int k2 = 0; k2 < 2; ++k2)
    pa[k2] = *(const short8*)(Ps + (wave * 16 + lr) * 64 + k2 * 32 + lq * 8);

  unsigned short* ob = out + h * 64;
  #pragma unroll
  for (int jd = 0; jd < 4; ++jd) {
    float4v a = (float4v){0.f, 0.f, 0.f, 0.f};
    #pragma unroll
    for (int k2 = 0; k2 < 2; ++k2) {
      short8 vf = *(const short8*)(Vt + (jd * 16 + lr) * 64 + k2 * 32 + lq * 8);
      a = __builtin_amdgcn_mfma_f32_16x16x32_bf16(pa[k2], vf, a, 0, 0, 0);
    }
    #pragma unroll
    for (int r = 0; r < 4; ++r) {
      const int row = wave * 16 + lq * 4 + r;
      ob[(size_t)(tok0 + row) * 1024 + jd * 16 + lr] = f2bf_bits(a[r]);
    }
  }
}

// ---------------- launch ---------------------------------------------------
extern "C" void kernel_launch(void* const* d_in, const int* in_sizes, int n_in,
                              void* d_out, int out_size, void* d_ws, size_t ws_size,
                              hipStream_t stream) {
  const float* x      = (const float*)d_in[0];  // [4,8192,1024]
  const float* w_qkv  = (const float*)d_in[1];  // [3072,1024]
  const float* b_qkv  = (const float*)d_in[2];  // [3072]
  const float* w_proj = (const float*)d_in[3];  // [1024,1024]
  const float* b_proj = (const float*)d_in[4];  // [1024]
  float* outp = (float*)d_out;                  // [4,8192,1024] fp32

  char* ws = (char*)d_ws;
  unsigned short* xb     = (unsigned short*)(ws);
  unsigned short* wqkvb  = (unsigned short*)(ws + 67108864);
  unsigned short* wprojb = (unsigned short*)(ws + 73400320);
  unsigned short* qkvb   = (unsigned short*)(ws + 75497472);
  unsigned short* attnb  = (unsigned short*)(ws + 276824064);

  cast_f32_to_bf16<<<32768, 256, 0, stream>>>(x,      xb,     33554432 / 4);
  cast_f32_to_bf16<<<3072,  256, 0, stream>>>(w_qkv,  wqkvb,  3145728 / 4);
  cast_f32_to_bf16<<<1024,  256, 0, stream>>>(w_proj, wprojb, 1048576 / 4);

  // qkv = x @ w_qkv^T + b_qkv : M=32768, N=3072, K=1024
  gemm_bt<true><<<256 * 24, 256, 0, stream>>>(xb, wqkvb, b_qkv, qkvb,
                                              32768, 3072, 1024, 256);
  // block-diagonal window attention: 4*16*128 = 8192 windows
  win_attn<<<8192, 256, 0, stream>>>(qkvb, attnb);
  // out = attn @ w_proj^T + b_proj : M=32768, N=1024, K=1024
  gemm_bt<false><<<256 * 8, 256, 0, stream>>>(attnb, wprojb, b_proj, outp,
                                              32768, 1024, 1024, 256);
}

// Round 2
// 658.481 us; speedup vs baseline: 1.0593x; 1.0593x over previous
//
#include <hip/hip_runtime.h>
#include <hip/hip_bf16.h>
#include <cstdint>
#include <cstddef>

// HierarchicalAttention on MI355X (gfx950).
// Pipeline: cast(x,wqkv,wproj)->bf16 | qkv GEMM (bf16 MFMA) | window attention
// (MFMA QK^T + fp32 softmax + MFMA PV) | proj GEMM (bf16 MFMA, fp32 out).
//
// R2 change: GROUP_M=8 block swizzle in gemm_bt for L2/L3 locality.
// R1 baseline: 697.5 us total; QKV GEMM 320 us, FETCH 655 MB (A re-streamed
// 9x because bm-fast order + 201 MB of writes evicts A from L3).
//
// Workspace layout (total 343,932,928 B):
//   [0)            x_bf16     [32768,1024]  67,108,864 B
//   [67108864)     wqkv_bf16  [3072,1024]    6,291,456 B
//   [73400320)     wproj_bf16 [1024,1024]    2,097,152 B
//   [75497472)     qkv_bf16   [32768,3072] 201,326,592 B
//   [276824064)    attn_bf16  [32768,1024]  67,108,864 B

typedef __attribute__((ext_vector_type(8))) short short8;
typedef __attribute__((ext_vector_type(4))) float float4v;

static __device__ __forceinline__ void async16(void* lds, const void* g) {
  // global -> LDS direct copy, 16B per lane; LDS dest = wave-uniform base + lane*16
  __builtin_amdgcn_global_load_lds((const __attribute__((address_space(1))) void*)g,
                                   (__attribute__((address_space(3))) void*)lds,
                                   16, 0, 0);
}

static __device__ __forceinline__ unsigned short f2bf_bits(float x) {
  unsigned int u = __float_as_uint(x);
  unsigned int r = (u + 0x7fffu + ((u >> 16) & 1u)) >> 16;  // RNE
  return (unsigned short)r;
}

// ---------------- cast fp32 -> bf16 (vectorized, n divisible by 1024) -------
__global__ __launch_bounds__(256) void cast_f32_to_bf16(
    const float* __restrict__ in, unsigned short* __restrict__ out, int n4) {
  int i = blockIdx.x * 256 + threadIdx.x;
  if (i >= n4) return;
  float4 v = ((const float4*)in)[i];
  ushort4 o;
  o.x = f2bf_bits(v.x); o.y = f2bf_bits(v.y);
  o.z = f2bf_bits(v.z); o.w = f2bf_bits(v.w);
  ((ushort4*)out)[i] = o;
}

// ---------------- GEMM: C[M,N] = A[M,K] * B[N,K]^T + bias ------------------
// m97 structure: 128x128 tile, BK=32, 4 waves in 2x2, each wave 64x64 (4x4
// tiles of mfma_f32_16x16x32_bf16), global_load_lds width=16 staging,
// 2-barrier K-loop. M,N,K divisible by 128/128/32; no bounds checks.
//
// Block swizzle: GROUP_M=8 consecutive bm per supergroup, bn-slow. With the
// XCD round-robin dispatch (blockIdx%8 -> XCD), bm = inG%8 pins one A-strip
// per XCD L2; A is fetched from HBM once instead of ntiles times.
template<bool OUT_BF16>
__global__ __launch_bounds__(256) void gemm_bt(
    const unsigned short* __restrict__ A,   // [M,K] bf16 bits
    const unsigned short* __restrict__ B,   // [N,K] bf16 bits
    const float* __restrict__ bias,         // [N]
    void* __restrict__ Cout,                // [M,N] bf16 or fp32
    int M, int N, int K, int ntiles)
{
  __shared__ unsigned short As[128 * 32];   // 8 KB
  __shared__ unsigned short Bs[128 * 32];   // 8 KB

  const int t    = threadIdx.x;
  const int wave = t >> 6;
  const int lane = t & 63;

  // GROUP_M=8 swizzle (mtiles divisible by 8 for both GEMMs)
  const int GM    = 8;
  const int group = blockIdx.x / (GM * ntiles);
  const int inG   = blockIdx.x % (GM * ntiles);
  const int bm    = group * GM + (inG % GM);
  const int bn    = inG / GM;

  const int wm   = (wave >> 1) * 64;
  const int wn   = (wave & 1) * 64;
  const int lr   = lane & 15;        // row within 16-tile for A/B frags
  const int lk   = (lane >> 4) * 8;  // k offset within BK=32

  // staging: thread t covers LDS elems [t*8, t*8+8) and [2048+t*8, ...)
  const int srow = t >> 2;           // 0..63
  const int scol = (t & 3) << 3;     // 0,8,16,24
  const unsigned short* Ag = A + (size_t)(bm * 128 + srow) * K + scol;
  const unsigned short* Bg = B + (size_t)(bn * 128 + srow) * K + scol;
  unsigned short* Asw = As + wave * 512;  // wave-uniform LDS base
  unsigned short* Bsw = Bs + wave * 512;

  float4v acc[4][4];
  #pragma unroll
  for (int i = 0; i < 4; ++i)
    #pragma unroll
    for (int j = 0; j < 4; ++j) acc[i][j] = (float4v){0.f, 0.f, 0.f, 0.f};

  for (int k0 = 0; k0 < K; k0 += 32) {
    async16(Asw,        Ag + k0);
    async16(Asw + 2048, Ag + (size_t)64 * K + k0);
    async16(Bsw,        Bg + k0);
    async16(Bsw + 2048, Bg + (size_t)64 * K + k0);
    __syncthreads();  // drains vmcnt (global_load_lds) + barrier

    short8 af[4], bfr[4];
    #pragma unroll
    for (int i = 0; i < 4; ++i)
      af[i] = *(const short8*)(As + (wm + i * 16 + lr) * 32 + lk);
    #pragma unroll
    for (int j = 0; j < 4; ++j)
      bfr[j] = *(const short8*)(Bs + (wn + j * 16 + lr) * 32 + lk);
    #pragma unroll
    for (int i = 0; i < 4; ++i)
      #pragma unroll
      for (int j = 0; j < 4; ++j)
        acc[i][j] = __builtin_amdgcn_mfma_f32_16x16x32_bf16(af[i], bfr[j], acc[i][j], 0, 0, 0);
    __syncthreads();  // protect LDS before next staging
  }

  // epilogue: C/D layout col=lane&15, row=(lane>>4)*4+reg (m89-verified)
  const int rbase = bm * 128 + wm + (lane >> 4) * 4;
  const int cbase = bn * 128 + wn + lr;
  #pragma unroll
  for (int j = 0; j < 4; ++j) {
    const int col = cbase + j * 16;
    const float bv = bias[col];
    #pragma unroll
    for (int i = 0; i < 4; ++i) {
      const int row = rbase + i * 16;
      #pragma unroll
      for (int r = 0; r < 4; ++r) {
        float v = acc[i][j][r] + bv;
        if (OUT_BF16)
          ((unsigned short*)Cout)[(size_t)(row + r) * N + col] = f2bf_bits(v);
        else
          ((float*)Cout)[(size_t)(row + r) * N + col] = v;
      }
    }
  }
}

// ---------------- window attention --------------------------------------
// One block (4 waves) per 64-token window. Wave w owns query strip
// [w*16, w*16+16). S=QK^T and O=PV via mfma_f32_16x16x32_bf16; softmax fp32.
__global__ __launch_bounds__(256) void win_attn(
    const unsigned short* __restrict__ qkv,  // [32768, 3072] bf16
    unsigned short* __restrict__ out)        // [32768, 1024] bf16
{
  __shared__ unsigned short Qs[64 * 64];  // 8 KB each
  __shared__ unsigned short Ks[64 * 64];
  __shared__ unsigned short Vt[64 * 64];  // V transposed: Vt[d][key]
  __shared__ unsigned short Ps[64 * 64];

  const int t    = threadIdx.x;
  const int wave = t >> 6;
  const int lane = t & 63;
  const int wid  = blockIdx.x;          // 0..8191
  const int h    = (wid >> 7) & 15;
  const int b    = wid >> 11;
  const int wi   = wid & 127;
  const int tok0 = b * 8192 + wi * 64;

  const unsigned short* qb = qkv + (size_t)tok0 * 3072 + h * 64;
  const unsigned short* kb = qb + 1024;
  const unsigned short* vb = qb + 2048;

  {
    // Q,K: async 16B/lane; LDS elem offset = t*8 + o*2048 (row-major [64][64])
    const int row = t >> 3;          // 0..31
    const int col = (t & 7) << 3;    // 0..56
    unsigned short* Qw = Qs + wave * 512;
    unsigned short* Kw = Ks + wave * 512;
    #pragma unroll
    for (int o = 0; o < 2; ++o) {
      async16(Qw + o * 2048, qb + (size_t)(o * 32 + row) * 3072 + col);
      async16(Kw + o * 2048, kb + (size_t)(o * 32 + row) * 3072 + col);
    }
    // V transposed: lane reads V[key][d0..d0+7], writes Vt[d][key]
    // (LDS write bank = (lane/2)%32 -> 2-way, free per m136)
    const int key = lane;
    const int d0  = wave * 8;
    #pragma unroll
    for (int o = 0; o < 2; ++o) {
      const int d = d0 + o * 32;
      ushort4 r0 = *(const ushort4*)(vb + (size_t)key * 3072 + d);
      ushort4 r1 = *(const ushort4*)(vb + (size_t)key * 3072 + d + 4);
      Vt[(d + 0) * 64 + key] = r0.x; Vt[(d + 1) * 64 + key] = r0.y;
      Vt[(d + 2) * 64 + key] = r0.z; Vt[(d + 3) * 64 + key] = r0.w;
      Vt[(d + 4) * 64 + key] = r1.x; Vt[(d + 5) * 64 + key] = r1.y;
      Vt[(d + 6) * 64 + key] = r1.z; Vt[(d + 7) * 64 + key] = r1.w;
    }
  }
  __syncthreads();

  const int lr = lane & 15;
  const int lq = lane >> 4;

  // S = Q K^T : A-frag rows = wave strip, contiguous ds_read_b128
  short8 qa[2];
  #pragma unroll
  for (int k2 = 0; k2 < 2; ++k2)
    qa[k2] = *(const short8*)(Qs + (wave * 16 + lr) * 64 + k2 * 32 + lq * 8);

  float4v s[4];
  #pragma unroll
  for (int jt = 0; jt < 4; ++jt) {
    float4v a = (float4v){0.f, 0.f, 0.f, 0.f};
    #pragma unroll
    for (int k2 = 0; k2 < 2; ++k2) {
      short8 kf = *(const short8*)(Ks + (jt * 16 + lr) * 64 + k2 * 32 + lq * 8);
      a = __builtin_amdgcn_mfma_f32_16x16x32_bf16(qa[k2], kf, a, 0, 0, 0);
    }
    s[jt] = a;
  }

  // softmax over keys; row = wave*16 + lq*4 + r, cols spread over jt (reg) and
  // lane&15 (16-lane groups share lq -> xor-shuffle 1,2,4,8)
  const float scale = 0.125f;  // 1/sqrt(64)
  float pr[4][4];
  #pragma unroll
  for (int r = 0; r < 4; ++r) {
    float m = s[0][r];
    #pragma unroll
    for (int jt = 1; jt < 4; ++jt) m = fmaxf(m, s[jt][r]);
    #pragma unroll
    for (int off = 1; off < 16; off <<= 1) m = fmaxf(m, __shfl_xor(m, off));
    float sum = 0.f;
    #pragma unroll
    for (int jt = 0; jt < 4; ++jt) {
      float e = __expf((s[jt][r] - m) * scale);
      pr[jt][r] = e; sum += e;
    }
    #pragma unroll
    for (int off = 1; off < 16; off <<= 1) sum += __shfl_xor(sum, off);
    float inv = 1.0f / sum;
    #pragma unroll
    for (int jt = 0; jt < 4; ++jt) pr[jt][r] *= inv;
  }

  // P: C-layout -> LDS -> A-layout (m120-verified round trip)
  #pragma unroll
  for (int jt = 0; jt < 4; ++jt)
    #pragma unroll
    for (int r = 0; r < 4; ++r)
      Ps[(wave * 16 + lq * 4 + r) * 64 + jt * 16 + lr] = f2bf_bits(pr[jt][r]);
  __syncthreads();

  short8 pa[2];
  #pragma unroll
  for (int k2 = 0; k2 < 2; ++k2)
    pa[k2] = *(const short8*)(Ps + (wave * 16 + lr) * 64 + k2 * 32 + lq * 8);

  unsigned short* ob = out + h * 64;
  #pragma unroll
  for (int jd = 0; jd < 4; ++jd) {
    float4v a = (float4v){0.f, 0.f, 0.f, 0.f};
    #pragma unroll
    for (int k2 = 0; k2 < 2; ++k2) {
      short8 vf = *(const short8*)(Vt + (jd * 16 + lr) * 64 + k2 * 32 + lq * 8);
      a = __builtin_amdgcn_mfma_f32_16x16x32_bf16(pa[k2], vf, a, 0, 0, 0);
    }
    #pragma unroll
    for (int r = 0; r < 4; ++r) {
      const int row = wave * 16 + lq * 4 + r;
      ob[(size_t)(tok0 + row) * 1024 + jd * 16 + lr] = f2bf_bits(a[r]);
    }
  }
}

// ---------------- launch ---------------------------------------------------
extern "C" void kernel_launch(void* const* d_in, const int* in_sizes, int n_in,
                              void* d_out, int out_size, void* d_ws, size_t ws_size,
                              hipStream_t stream) {
  const float* x      = (const float*)d_in[0];  // [4,8192,1024]
  const float* w_qkv  = (const float*)d_in[1];  // [3072,1024]
  const float* b_qkv  = (const float*)d_in[2];  // [3072]
  const float* w_proj = (const float*)d_in[3];  // [1024,1024]
  const float* b_proj = (const float*)d_in[4];  // [1024]
  float* outp = (float*)d_out;                  // [4,8192,1024] fp32

  char* ws = (char*)d_ws;
  unsigned short* xb     = (unsigned short*)(ws);
  unsigned short* wqkvb  = (unsigned short*)(ws + 67108864);
  unsigned short* wprojb = (unsigned short*)(ws + 73400320);
  unsigned short* qkvb   = (unsigned short*)(ws + 75497472);
  unsigned short* attnb  = (unsigned short*)(ws + 276824064);

  cast_f32_to_bf16<<<32768, 256, 0, stream>>>(x,      xb,     33554432 / 4);
  cast_f32_to_bf16<<<3072,  256, 0, stream>>>(w_qkv,  wqkvb,  3145728 / 4);
  cast_f32_to_bf16<<<1024,  256, 0, stream>>>(w_proj, wprojb, 1048576 / 4);

  // qkv = x @ w_qkv^T + b_qkv : M=32768, N=3072, K=1024 (mtiles=256, ntiles=24)
  gemm_bt<true><<<256 * 24, 256, 0, stream>>>(xb, wqkvb, b_qkv, qkvb,
                                              32768, 3072, 1024, 24);
  // block-diagonal window attention: 4*16*128 = 8192 windows
  win_attn<<<8192, 256, 0, stream>>>(qkvb, attnb);
  // out = attn @ w_proj^T + b_proj : M=32768, N=1024, K=1024 (ntiles=8)
  gemm_bt<false><<<256 * 8, 256, 0, stream>>>(attnb, wprojb, b_proj, outp,
                                              32768, 1024, 1024, 8);
}